// Round 6
// baseline (980.792 us; speedup 1.0000x reference)
//
#include <hip/hip_runtime.h>
#include <hip/hip_bf16.h>

// SplineCNN block.
// conv1, conv2 (CIN=32): fused S-scheme -- per-16-node block, aggregate
//   S[slot][27*32 + 32] in LDS fp32 (spline bins + self-x for root), scale bins
//   by 1/deg, then MFMA GEMM 16x896 @ 896xCOUT with [W;root] packed as B-frags.
// conv3 (CIN=96>COUT=32): Z-scheme -- Z[s,k,o]=h3[s]·W3[k,:,o] dense MFMA GEMM,
//   then register-only gather-aggregate.
// All scratch in __device__ statics referenced only from device code.

#define EPS 1e-5f
#define MAXN 50176
#define MAXE 401408
#define SPITCH 900   // 896 + 4 pad words: rows m, m+8 share banks (2-way = free)

typedef __attribute__((ext_vector_type(8))) short short8;
typedef __attribute__((ext_vector_type(4))) float floatx4;

__device__ int             g_deg[MAXN];
__device__ int             g_offs[MAXN + 1];
__device__ int             g_cursor[MAXN];
__device__ int             g_eidx[MAXE];
__device__ float           g_basis[MAXE * 8];
__device__ unsigned char   g_widx[MAXE * 8];
__device__ __align__(16) __hip_bfloat16 g_h0[MAXN * 32];
__device__ __align__(16) __hip_bfloat16 g_h1[MAXN * 32];
__device__ __align__(16) __hip_bfloat16 g_h2[MAXN * 64];
__device__ __align__(16) __hip_bfloat16 g_h3[MAXN * 96];
__device__ __align__(16) __hip_bfloat16 g_Z[(size_t)MAXN * 896];
__device__ __align__(16) __hip_bfloat16 g_Wp[86016];
__device__ float           g_stats[128];
__device__ float           g_coef[128];
__device__ int             g_isbf16;

__device__ __forceinline__ float loadf(const void* p, int i, bool bf)
{
    return bf ? (float)((const __hip_bfloat16*)p)[i] : ((const float*)p)[i];
}

// ---------------- wire dtype detection (one wave) ----------------
__global__ void detect_kernel(const unsigned int* __restrict__ w)
{
    int lane = threadIdx.x;
    int cnt = 0;
    for (int i = lane; i < 256; i += 64) {
        unsigned int lo = w[i] & 0xFFFFu;
        int ex = (int)((lo >> 7) & 0xFFu);
        if (lo == 0u || (ex >= 96 && ex <= 140)) cnt++;
    }
#pragma unroll
    for (int o = 1; o < 64; o <<= 1) cnt += __shfl_xor(cnt, o, 64);
    if (lane == 0) g_isbf16 = (cnt >= 200) ? 1 : 0;
}

// ---------------- zero-init scratch ----------------
__global__ void init_kernel(int n)
{
    int i = blockIdx.x * blockDim.x + threadIdx.x;
    if (i < n) { g_deg[i] = 0; g_cursor[i] = 0; }
    if (i < 128) g_stats[i] = 0.0f;
}

// ---------------- per-edge basis + widx + degree count ----------------
__global__ void basis_kernel(const void* __restrict__ attr,
                             const int* __restrict__ dst, int E)
{
    int e = blockIdx.x * blockDim.x + threadIdx.x;
    if (e >= E) return;
    const bool bf = (g_isbf16 != 0);
    float f[3];
    int lo[3];
#pragma unroll
    for (int d = 0; d < 3; ++d) {
        float a = loadf(attr, e * 3 + d, bf);
        float s = a * 3.0f;
        float l = floorf(s);
        lo[d] = (int)l;
        f[d] = s - l;
    }
    const int p3[3] = {1, 3, 9};
#pragma unroll
    for (int b = 0; b < 8; ++b) {
        float w = 1.0f;
        int id = 0;
#pragma unroll
        for (int d = 0; d < 3; ++d) {
            int bit = (b >> d) & 1;
            w *= bit ? f[d] : (1.0f - f[d]);
            id += ((lo[d] + bit) % 3) * p3[d];
        }
        g_basis[e * 8 + b] = w;
        g_widx[e * 8 + b] = (unsigned char)id;
    }
    atomicAdd(&g_deg[dst[e]], 1);
}

// ---------------- exclusive scan (single block) ----------------
__global__ void scan_kernel(int n, int chunk)
{
    __shared__ int buf[1024];
    int tid = threadIdx.x;
    int begin = tid * chunk;
    int end = begin + chunk; if (end > n) end = n;
    int s = 0;
    for (int i = begin; i < end; ++i) s += g_deg[i];
    buf[tid] = s;
    __syncthreads();
    for (int o = 1; o < 1024; o <<= 1) {
        int t = (tid >= o) ? buf[tid - o] : 0;
        __syncthreads();
        buf[tid] += t;
        __syncthreads();
    }
    int base = buf[tid] - s;
    for (int i = begin; i < end; ++i) { g_offs[i] = base; base += g_deg[i]; }
    if (tid == 1023) g_offs[n] = buf[1023];
}

// ---------------- CSR fill ----------------
__global__ void fill_kernel(const int* __restrict__ dst, int E)
{
    int e = blockIdx.x * blockDim.x + threadIdx.x;
    if (e >= E) return;
    int d = dst[e];
    int p = atomicAdd(&g_cursor[d], 1);
    g_eidx[g_offs[d] + p] = e;
}

// ---------------- cast external x -> g_h0 bf16 ----------------
__global__ void cast_x(const void* __restrict__ x, int total)
{
    int t = blockIdx.x * blockDim.x + threadIdx.x;
    if (t >= total) return;
    g_h0[t] = __float2bfloat16(loadf(x, t, g_isbf16 != 0));
}

// ---------------- pack [W;root] (K=896, CIN=32) into MFMA B-fragments ------
// g_Wp[(((nt*28)+kk)*64 + lane)*8 + j]; k = kk*32+(lane>>4)*8+j; o = nt*16+(lane&15)
template <int COUT>
__global__ void prep_w_s(const void* __restrict__ W, const void* __restrict__ root,
                         int total)
{
    int t = blockIdx.x * blockDim.x + threadIdx.x;
    if (t >= total) return;
    const bool bf = (g_isbf16 != 0);
    int j = t & 7;
    int lane = (t >> 3) & 63;
    int rest = t >> 9;
    int kk = rest % 28;
    int nt = rest / 28;
    int k = kk * 32 + (lane >> 4) * 8 + j;
    int o = nt * 16 + (lane & 15);
    float v;
    if (k < 864) v = loadf(W, ((k >> 5) * 32 + (k & 31)) * COUT + o, bf);
    else         v = loadf(root, (k - 864) * COUT + o, bf);
    g_Wp[t] = __float2bfloat16(v);
}

// ---------------- fused conv (CIN=32): LDS-S aggregate + MFMA GEMM ----------
// IN_SEL: 0 = g_h0, 1 = g_h1.  OUT_SEL: 1 = g_h1, 2 = g_h2, 0 = external.
template <int COUT, bool ELU, int IN_SEL, int OUT_SEL>
__global__ __launch_bounds__(256) void fused_conv(const int* __restrict__ src,
                                                  const void* __restrict__ bias,
                                                  void* __restrict__ out_ext, int N)
{
    __shared__ float S[16 * SPITCH];     // 57.6 KB
    int tid = threadIdx.x, wid = tid >> 6, lane = tid & 63;
    int nbase = blockIdx.x * 16;
    const bool bf = (g_isbf16 != 0);

    for (int i = tid; i < 16 * SPITCH; i += 256) S[i] = 0.0f;
    __syncthreads();

    // ---- phase 1: aggregate. wave wid handles slots wid*4..wid*4+3 ----
    int c = lane & 31, bh = lane >> 5;
    for (int s = 0; s < 4; ++s) {
        int slot = wid * 4 + s;
        int n = nbase + slot;
        if (n >= N) break;
        float* Srow = S + slot * SPITCH;
        float xs = (IN_SEL == 0) ? (float)g_h0[n * 32 + c] : (float)g_h1[n * 32 + c];
        if (bh == 0) Srow[864 + c] = xs;        // self-x -> root columns
        int e0 = g_offs[n], e1 = g_offs[n + 1];
        for (int ei = e0; ei < e1; ++ei) {
            int e = g_eidx[ei];
            int sn = src[e];
            float xv = (IN_SEL == 0) ? (float)g_h0[sn * 32 + c]
                                     : (float)g_h1[sn * 32 + c];
#pragma unroll
            for (int bi = 0; bi < 4; ++bi) {
                int b = bh * 4 + bi;
                float bs = g_basis[e * 8 + b];
                int wx = (int)g_widx[e * 8 + b];
                Srow[wx * 32 + c] += bs * xv;   // 8 wx distinct per edge: race-free
            }
        }
    }
    __syncthreads();

    // ---- scale spline bins by 1/deg (root cols untouched) ----
    for (int slot = 0; slot < 16; ++slot) {
        int n = nbase + slot;
        int deg = (n < N) ? g_offs[n + 1] - g_offs[n] : 1;
        float inv = 1.0f / (float)(deg < 1 ? 1 : deg);
        for (int cc = tid; cc < 864; cc += 256) S[slot * SPITCH + cc] *= inv;
    }
    __syncthreads();

    // ---- phase 2: GEMM 16 x 896 @ 896 x COUT; wave wid = col-tile wid ----
    if (wid * 16 < COUT) {
        int m = lane & 15, quad = lane >> 4;
        const float* Abase = S + m * SPITCH + quad * 8;
        floatx4 acc = {};
#pragma unroll
        for (int kk = 0; kk < 28; ++kk) {
            union { __hip_bfloat16 h[8]; short8 v; } u;
            const float* ap = Abase + kk * 32;
#pragma unroll
            for (int j = 0; j < 8; ++j) u.h[j] = __float2bfloat16(ap[j]);
            const short* bp = (const short*)g_Wp +
                ((size_t)(wid * 28 + kk) * 64 + lane) * 8;
            short8 b = *(const short8*)bp;
            acc = __builtin_amdgcn_mfma_f32_16x16x32_bf16(u.v, b, acc, 0, 0, 0);
        }
        int o = wid * 16 + (lane & 15);
        float bval = loadf(bias, o, bf);
#pragma unroll
        for (int r = 0; r < 4; ++r) {
            int slot = quad * 4 + r;
            int n = nbase + slot;
            if (n >= N) continue;
            float v = acc[r] + bval;
            if (ELU) v = v > 0.0f ? v : expm1f(v);
            if (OUT_SEL == 1)      g_h1[n * 32 + o] = __float2bfloat16(v);
            else if (OUT_SEL == 2) g_h2[n * 64 + o] = __float2bfloat16(v);
            else {
                if (bf) ((__hip_bfloat16*)out_ext)[n * COUT + o] = __float2bfloat16(v);
                else    ((float*)out_ext)[n * COUT + o] = v;
            }
        }
    }
}

// ---------------- conv3 Z-path: pack W3+root3 into B-fragments ----------------
template <int CIN, int COUT, int KPAD>
__global__ void prep_w(const void* __restrict__ W, const void* __restrict__ root,
                       int total)
{
    int t = blockIdx.x * blockDim.x + threadIdx.x;
    if (t >= total) return;
    const bool bf = (g_isbf16 != 0);
    const int KB = KPAD / 32;
    int j = t & 7;
    int lane = (t >> 3) & 63;
    int rest = t >> 9;
    int kk = rest % KB;
    int nt = rest / KB;
    int k = kk * 32 + (lane >> 4) * 8 + j;
    int ncol = nt * 16 + (lane & 15);
    int kw = ncol / COUT;
    int o = ncol - kw * COUT;
    float v = 0.0f;
    if (k < CIN)
        v = (kw < 27) ? loadf(W, (kw * CIN + k) * COUT + o, bf)
                      : loadf(root, k * COUT + o, bf);
    g_Wp[t] = __float2bfloat16(v);
}

// ---------------- conv3 Z-path: dense GEMM Z = h3 @ Wp ----------------
template <int STRIDE, int NTOT, int KPAD, int NPW>
__global__ __launch_bounds__(256) void gemm_kernel(int MT, int NTW)
{
    int gid = blockIdx.x * 256 + threadIdx.x;
    int gw = gid >> 6, lane = gid & 63;
    if (gw >= MT * NTW) return;
    int mt = gw % MT;
    int ntb = (gw / MT) * NPW;
    int m = lane & 15, quad = lane >> 4;
    const short* hrow = (const short*)g_h3 + (size_t)(mt * 16 + m) * STRIDE;
    floatx4 acc[NPW] = {};
    const int KB = KPAD / 32;
#pragma unroll
    for (int kk = 0; kk < KB; ++kk) {
        short8 a = *(const short8*)(hrow + kk * 32 + quad * 8);
#pragma unroll
        for (int i = 0; i < NPW; ++i) {
            const short* bp = (const short*)g_Wp +
                (((size_t)(ntb + i) * KB + kk) * 64 + lane) * 8;
            short8 b = *(const short8*)bp;
            acc[i] = __builtin_amdgcn_mfma_f32_16x16x32_bf16(a, b, acc[i], 0, 0, 0);
        }
    }
    int col = lane & 15;
    int rowbase = mt * 16 + quad * 4;
#pragma unroll
    for (int i = 0; i < NPW; ++i) {
        int ncol = (ntb + i) * 16 + col;
#pragma unroll
        for (int r = 0; r < 4; ++r)
            g_Z[(size_t)(rowbase + r) * NTOT + ncol] = __float2bfloat16(acc[i][r]);
    }
}

// ---------------- conv3 Z-path: gather-aggregate (COUT=32) ----------------
template <int COUT, int NTOT>
__global__ __launch_bounds__(256) void agg_kernel(const int* __restrict__ src,
                                                  const void* __restrict__ bias,
                                                  void* __restrict__ out_ext, int N)
{
    int wid = threadIdx.x >> 6, lane = threadIdx.x & 63;
    int n = blockIdx.x * 4 + wid;
    if (n >= N) return;
    const bool bf = (g_isbf16 != 0);
    int e0 = g_offs[n], e1 = g_offs[n + 1];
    float acc = 0.0f;
    int o = lane & 31, bh = lane >> 5;
    for (int ei = e0; ei < e1; ++ei) {
        int e = g_eidx[ei];
        const __hip_bfloat16* zr = g_Z + (size_t)src[e] * NTOT;
#pragma unroll
        for (int bi = 0; bi < 4; ++bi) {
            int b = bh + bi * 2;
            float bs = g_basis[e * 8 + b];
            int wx = (int)g_widx[e * 8 + b];
            acc += bs * (float)zr[wx * 32 + o];
        }
    }
    acc += __shfl_xor(acc, 32, 64);
    if (lane >= 32) return;
    int deg = e1 - e0;
    float inv = 1.0f / (float)(deg < 1 ? 1 : deg);
    float v = acc * inv + (float)g_Z[(size_t)n * NTOT + 27 * COUT + o]
            + loadf(bias, o, bf);
    if (bf) ((__hip_bfloat16*)out_ext)[n * COUT + o] = __float2bfloat16(v);
    else    ((float*)out_ext)[n * COUT + o] = v;
}

// ---------------- BN stats ----------------
__global__ void bn_reduce(int n)
{
    int tid = threadIdx.x;
    int c = tid & 63;
    int r = tid >> 6;
    float s = 0.0f, s2 = 0.0f;
    for (int i = blockIdx.x * 4 + r; i < n; i += gridDim.x * 4) {
        float v = (float)g_h2[i * 64 + c];
        s += v; s2 += v * v;
    }
    __shared__ float b1s[256], b2s[256];
    b1s[tid] = s; b2s[tid] = s2;
    __syncthreads();
    if (r == 0) {
        s  = b1s[c] + b1s[c + 64] + b1s[c + 128] + b1s[c + 192];
        s2 = b2s[c] + b2s[c + 64] + b2s[c + 128] + b2s[c + 192];
        atomicAdd(&g_stats[c], s);
        atomicAdd(&g_stats[64 + c], s2);
    }
}

__global__ void bn_coef(const void* __restrict__ gamma,
                        const void* __restrict__ beta, int n)
{
    int c = threadIdx.x;
    const bool bf = (g_isbf16 != 0);
    float inv_n = 1.0f / (float)n;
    float mu = g_stats[c] * inv_n;
    float var = g_stats[64 + c] * inv_n - mu * mu;
    float A = rsqrtf(var + EPS) * loadf(gamma, c, bf);
    g_coef[c] = A;
    g_coef[64 + c] = loadf(beta, c, bf) - mu * A;
}

// ---------------- h3 = [elu(bn(h2)), pos, 0-pad] (96 ch) ----------------
__global__ void h3_build(const void* __restrict__ pos, int N)
{
    int t = blockIdx.x * blockDim.x + threadIdx.x;
    if (t >= N * 96) return;
    int n = t / 96, ch = t - n * 96;
    const bool bf = (g_isbf16 != 0);
    float v;
    if (ch < 64) {
        float h = (float)g_h2[n * 64 + ch];
        v = h * g_coef[ch] + g_coef[64 + ch];
        v = v > 0.0f ? v : expm1f(v);
    } else if (ch < 67) {
        v = loadf(pos, n * 3 + (ch - 64), bf);
    } else {
        v = 0.0f;
    }
    g_h3[(size_t)n * 96 + ch] = __float2bfloat16(v);
}

extern "C" void kernel_launch(void* const* d_in, const int* in_sizes, int n_in,
                              void* d_out, int out_size, void* d_ws, size_t ws_size,
                              hipStream_t stream)
{
    const void* x      = d_in[0];
    const int*  eindex = (const int*)d_in[1];
    const void* eattr  = d_in[2];
    const void* pos    = d_in[3];
    const void* W1     = d_in[4];
    const void* root1  = d_in[5];
    const void* b1     = d_in[6];
    const void* W2     = d_in[7];
    const void* root2  = d_in[8];
    const void* b2     = d_in[9];
    const void* gamma  = d_in[10];
    const void* beta   = d_in[11];
    const void* W3     = d_in[12];
    const void* root3  = d_in[13];
    const void* b3     = d_in[14];
    (void)d_ws; (void)ws_size; (void)n_in; (void)out_size;

    const int N = in_sizes[0] / 32;
    const int E = in_sizes[1] / 2;
    const int* srcp = eindex;
    const int* dstp = eindex + E;

    detect_kernel<<<1, 64, 0, stream>>>((const unsigned int*)x);
    init_kernel<<<(N + 255) / 256, 256, 0, stream>>>(N);

    int eb = (E + 255) / 256;
    basis_kernel<<<eb, 256, 0, stream>>>(eattr, dstp, E);
    int chunk = (N + 1023) / 1024;
    scan_kernel<<<1, 1024, 0, stream>>>(N, chunk);
    fill_kernel<<<eb, 256, 0, stream>>>(dstp, E);
    cast_x<<<(N * 32 + 255) / 256, 256, 0, stream>>>(x, N * 32);

    int nb16 = (N + 15) / 16;

    // ---- conv1: fused S-scheme, g_h0(32) -> g_h1(32), ELU ----
    {
        int wtot = (32 / 16) * 28 * 512;   // 28672
        prep_w_s<32><<<(wtot + 255) / 256, 256, 0, stream>>>(W1, root1, wtot);
        fused_conv<32, true, 0, 1><<<nb16, 256, 0, stream>>>(srcp, b1, nullptr, N);
    }
    // ---- conv2: fused S-scheme, g_h1(32) -> g_h2(64), raw ----
    {
        int wtot = (64 / 16) * 28 * 512;   // 57344
        prep_w_s<64><<<(wtot + 255) / 256, 256, 0, stream>>>(W2, root2, wtot);
        fused_conv<64, false, 1, 2><<<nb16, 256, 0, stream>>>(srcp, b2, nullptr, N);
    }
    // ---- BN + h3 build ----
    bn_reduce<<<120, 256, 0, stream>>>(N);
    bn_coef<<<1, 64, 0, stream>>>(gamma, beta, N);
    h3_build<<<(N * 96 + 255) / 256, 256, 0, stream>>>(pos, N);
    // ---- conv3: Z-scheme, h3(96) -> Z(896) -> out(32) ----
    {
        const int NTOT = 28 * 32, KPAD = 96, NPW = 4;
        int wtot = (NTOT / 16) * (KPAD / 32) * 512;   // 86016
        prep_w<67, 32, KPAD><<<(wtot + 255) / 256, 256, 0, stream>>>(W3, root3, wtot);
        int NTW = (NTOT / 16) / NPW;                  // 14
        int MT = nb16;
        int waves = MT * NTW;
        gemm_kernel<96, NTOT, KPAD, NPW><<<(waves + 3) / 4, 256, 0, stream>>>(MT, NTW);
        agg_kernel<32, NTOT><<<(N + 3) / 4, 256, 0, stream>>>(srcp, b3, d_out, N);
    }
}

// Round 7
// 652.144 us; speedup vs baseline: 1.5039x; 1.5039x over previous
//
#include <hip/hip_runtime.h>
#include <hip/hip_bf16.h>

// SplineCNN block.
// conv1, conv2 (CIN=32): fused S-scheme, 1024-thr blocks / 16 nodes:
//   phase 1: ONE WAVE PER NODE builds S[slot][27*32+32] in LDS fp32
//            (spline bins scaled 1/deg + self-x for root), 32 waves/CU occupancy.
//   phase 2: waves 0..COUT/16-1 MFMA-GEMM 16x896 @ 896xCOUT ([W;root] B-frags).
// conv3 (CIN=96>COUT=32): Z-scheme -- Z=h3·[W3;root3] dense MFMA GEMM, then
//   register-only gather-aggregate (proven round-5 path).

#define EPS 1e-5f
#define MAXN 50176
#define MAXE 401408
#define SPITCH 900   // 896 + 4 pad words

typedef __attribute__((ext_vector_type(8))) short short8;
typedef __attribute__((ext_vector_type(4))) float floatx4;

__device__ int             g_deg[MAXN];
__device__ int             g_offs[MAXN + 1];
__device__ int             g_cursor[MAXN];
__device__ int             g_eidx[MAXE];
__device__ float           g_basis[MAXE * 8];
__device__ unsigned char   g_widx[MAXE * 8];
__device__ __align__(16) __hip_bfloat16 g_h0[MAXN * 32];
__device__ __align__(16) __hip_bfloat16 g_h1[MAXN * 32];
__device__ __align__(16) __hip_bfloat16 g_h2[MAXN * 64];
__device__ __align__(16) __hip_bfloat16 g_h3[MAXN * 96];
__device__ __align__(16) __hip_bfloat16 g_Z[(size_t)MAXN * 896];
__device__ __align__(16) __hip_bfloat16 g_Wp[86016];
__device__ float           g_stats[128];
__device__ float           g_coef[128];
__device__ int             g_isbf16;

__device__ __forceinline__ float loadf(const void* p, int i, bool bf)
{
    return bf ? (float)((const __hip_bfloat16*)p)[i] : ((const float*)p)[i];
}

// ---------------- wire dtype detection (one wave) ----------------
__global__ void detect_kernel(const unsigned int* __restrict__ w)
{
    int lane = threadIdx.x;
    int cnt = 0;
    for (int i = lane; i < 256; i += 64) {
        unsigned int lo = w[i] & 0xFFFFu;
        int ex = (int)((lo >> 7) & 0xFFu);
        if (lo == 0u || (ex >= 96 && ex <= 140)) cnt++;
    }
#pragma unroll
    for (int o = 1; o < 64; o <<= 1) cnt += __shfl_xor(cnt, o, 64);
    if (lane == 0) g_isbf16 = (cnt >= 200) ? 1 : 0;
}

// ---------------- zero-init scratch ----------------
__global__ void init_kernel(int n)
{
    int i = blockIdx.x * blockDim.x + threadIdx.x;
    if (i < n) { g_deg[i] = 0; g_cursor[i] = 0; }
    if (i < 128) g_stats[i] = 0.0f;
}

// ---------------- per-edge basis + widx + degree count ----------------
__global__ void basis_kernel(const void* __restrict__ attr,
                             const int* __restrict__ dst, int E)
{
    int e = blockIdx.x * blockDim.x + threadIdx.x;
    if (e >= E) return;
    const bool bf = (g_isbf16 != 0);
    float f[3];
    int lo[3];
#pragma unroll
    for (int d = 0; d < 3; ++d) {
        float a = loadf(attr, e * 3 + d, bf);
        float s = a * 3.0f;
        float l = floorf(s);
        lo[d] = (int)l;
        f[d] = s - l;
    }
    const int p3[3] = {1, 3, 9};
#pragma unroll
    for (int b = 0; b < 8; ++b) {
        float w = 1.0f;
        int id = 0;
#pragma unroll
        for (int d = 0; d < 3; ++d) {
            int bit = (b >> d) & 1;
            w *= bit ? f[d] : (1.0f - f[d]);
            id += ((lo[d] + bit) % 3) * p3[d];
        }
        g_basis[e * 8 + b] = w;
        g_widx[e * 8 + b] = (unsigned char)id;
    }
    atomicAdd(&g_deg[dst[e]], 1);
}

// ---------------- exclusive scan (single block) ----------------
__global__ void scan_kernel(int n, int chunk)
{
    __shared__ int buf[1024];
    int tid = threadIdx.x;
    int begin = tid * chunk;
    int end = begin + chunk; if (end > n) end = n;
    int s = 0;
    for (int i = begin; i < end; ++i) s += g_deg[i];
    buf[tid] = s;
    __syncthreads();
    for (int o = 1; o < 1024; o <<= 1) {
        int t = (tid >= o) ? buf[tid - o] : 0;
        __syncthreads();
        buf[tid] += t;
        __syncthreads();
    }
    int base = buf[tid] - s;
    for (int i = begin; i < end; ++i) { g_offs[i] = base; base += g_deg[i]; }
    if (tid == 1023) g_offs[n] = buf[1023];
}

// ---------------- CSR fill ----------------
__global__ void fill_kernel(const int* __restrict__ dst, int E)
{
    int e = blockIdx.x * blockDim.x + threadIdx.x;
    if (e >= E) return;
    int d = dst[e];
    int p = atomicAdd(&g_cursor[d], 1);
    g_eidx[g_offs[d] + p] = e;
}

// ---------------- cast external x -> g_h0 bf16 ----------------
__global__ void cast_x(const void* __restrict__ x, int total)
{
    int t = blockIdx.x * blockDim.x + threadIdx.x;
    if (t >= total) return;
    g_h0[t] = __float2bfloat16(loadf(x, t, g_isbf16 != 0));
}

// ---------------- pack [W;root] (K=896, CIN=32) into MFMA B-fragments ------
template <int COUT>
__global__ void prep_w_s(const void* __restrict__ W, const void* __restrict__ root,
                         int total)
{
    int t = blockIdx.x * blockDim.x + threadIdx.x;
    if (t >= total) return;
    const bool bf = (g_isbf16 != 0);
    int j = t & 7;
    int lane = (t >> 3) & 63;
    int rest = t >> 9;
    int kk = rest % 28;
    int nt = rest / 28;
    int k = kk * 32 + (lane >> 4) * 8 + j;
    int o = nt * 16 + (lane & 15);
    float v;
    if (k < 864) v = loadf(W, ((k >> 5) * 32 + (k & 31)) * COUT + o, bf);
    else         v = loadf(root, (k - 864) * COUT + o, bf);
    g_Wp[t] = __float2bfloat16(v);
}

// ---------------- fused conv (CIN=32): wave-per-node S + MFMA GEMM ----------
// IN_SEL: 0 = g_h0, 1 = g_h1.  OUT_SEL: 1 = g_h1, 2 = g_h2, 0 = external.
template <int COUT, bool ELU, int IN_SEL, int OUT_SEL>
__global__ __launch_bounds__(1024, 8) void fused_conv(const int* __restrict__ src,
                                                      const void* __restrict__ bias,
                                                      void* __restrict__ out_ext,
                                                      int N)
{
    __shared__ float S[16 * SPITCH];     // 57.6 KB
    int tid = threadIdx.x, wid = tid >> 6, lane = tid & 63;
    int nbase = blockIdx.x * 16;
    const bool bf = (g_isbf16 != 0);

    for (int i = tid; i < 16 * SPITCH; i += 1024) S[i] = 0.0f;
    __syncthreads();

    // ---- phase 1: wave `wid` aggregates node nbase+wid into S[wid] ----
    int n = nbase + wid;
    if (n < N) {
        float* Srow = S + wid * SPITCH;
        int c = lane & 31, bh = lane >> 5;
        float xs = (IN_SEL == 0) ? (float)g_h0[n * 32 + c] : (float)g_h1[n * 32 + c];
        if (bh == 0) Srow[864 + c] = xs;        // self-x -> root columns
        int e0 = g_offs[n], e1 = g_offs[n + 1];
        for (int ei = e0; ei < e1; ++ei) {
            int e = g_eidx[ei];
            int sn = src[e];
            float xv = (IN_SEL == 0) ? (float)g_h0[sn * 32 + c]
                                     : (float)g_h1[sn * 32 + c];
#pragma unroll
            for (int bi = 0; bi < 4; ++bi) {
                int b = bh * 4 + bi;
                float bs = g_basis[e * 8 + b];
                int wx = (int)g_widx[e * 8 + b];
                Srow[wx * 32 + c] += bs * xv;   // 8 wx distinct per edge: race-free
            }
        }
        // scale spline bins by 1/deg (root cols untouched); own row -> no barrier
        int deg = e1 - e0;
        float inv = 1.0f / (float)(deg < 1 ? 1 : deg);
        for (int cc = lane; cc < 864; cc += 64) Srow[cc] *= inv;
    }
    __syncthreads();

    // ---- phase 2: wave w = col-tile w of GEMM 16 x 896 @ 896 x COUT ----
    if (wid * 16 < COUT) {
        int m = lane & 15, quad = lane >> 4;
        const float* Abase = S + m * SPITCH + quad * 8;
        floatx4 acc = {};
#pragma unroll
        for (int kk = 0; kk < 28; ++kk) {
            union { __hip_bfloat16 h[8]; short8 v; } u;
            const float* ap = Abase + kk * 32;
#pragma unroll
            for (int j = 0; j < 8; ++j) u.h[j] = __float2bfloat16(ap[j]);
            const short* bp = (const short*)g_Wp +
                ((size_t)(wid * 28 + kk) * 64 + lane) * 8;
            short8 b = *(const short8*)bp;
            acc = __builtin_amdgcn_mfma_f32_16x16x32_bf16(u.v, b, acc, 0, 0, 0);
        }
        int o = wid * 16 + (lane & 15);
        float bval = loadf(bias, o, bf);
#pragma unroll
        for (int r = 0; r < 4; ++r) {
            int slot = quad * 4 + r;
            int nn = nbase + slot;
            if (nn >= N) continue;
            float v = acc[r] + bval;
            if (ELU) v = v > 0.0f ? v : expm1f(v);
            if (OUT_SEL == 1)      g_h1[nn * 32 + o] = __float2bfloat16(v);
            else if (OUT_SEL == 2) g_h2[nn * 64 + o] = __float2bfloat16(v);
            else {
                if (bf) ((__hip_bfloat16*)out_ext)[nn * COUT + o] = __float2bfloat16(v);
                else    ((float*)out_ext)[nn * COUT + o] = v;
            }
        }
    }
}

// ---------------- conv3 Z-path: pack W3+root3 into B-fragments ----------------
template <int CIN, int COUT, int KPAD>
__global__ void prep_w(const void* __restrict__ W, const void* __restrict__ root,
                       int total)
{
    int t = blockIdx.x * blockDim.x + threadIdx.x;
    if (t >= total) return;
    const bool bf = (g_isbf16 != 0);
    const int KB = KPAD / 32;
    int j = t & 7;
    int lane = (t >> 3) & 63;
    int rest = t >> 9;
    int kk = rest % KB;
    int nt = rest / KB;
    int k = kk * 32 + (lane >> 4) * 8 + j;
    int ncol = nt * 16 + (lane & 15);
    int kw = ncol / COUT;
    int o = ncol - kw * COUT;
    float v = 0.0f;
    if (k < CIN)
        v = (kw < 27) ? loadf(W, (kw * CIN + k) * COUT + o, bf)
                      : loadf(root, k * COUT + o, bf);
    g_Wp[t] = __float2bfloat16(v);
}

// ---------------- conv3 Z-path: dense GEMM Z = h3 @ Wp ----------------
template <int STRIDE, int NTOT, int KPAD, int NPW>
__global__ __launch_bounds__(256) void gemm_kernel(int MT, int NTW)
{
    int gid = blockIdx.x * 256 + threadIdx.x;
    int gw = gid >> 6, lane = gid & 63;
    if (gw >= MT * NTW) return;
    int mt = gw % MT;
    int ntb = (gw / MT) * NPW;
    int m = lane & 15, quad = lane >> 4;
    const short* hrow = (const short*)g_h3 + (size_t)(mt * 16 + m) * STRIDE;
    floatx4 acc[NPW] = {};
    const int KB = KPAD / 32;
#pragma unroll
    for (int kk = 0; kk < KB; ++kk) {
        short8 a = *(const short8*)(hrow + kk * 32 + quad * 8);
#pragma unroll
        for (int i = 0; i < NPW; ++i) {
            const short* bp = (const short*)g_Wp +
                (((size_t)(ntb + i) * KB + kk) * 64 + lane) * 8;
            short8 b = *(const short8*)bp;
            acc[i] = __builtin_amdgcn_mfma_f32_16x16x32_bf16(a, b, acc[i], 0, 0, 0);
        }
    }
    int col = lane & 15;
    int rowbase = mt * 16 + quad * 4;
#pragma unroll
    for (int i = 0; i < NPW; ++i) {
        int ncol = (ntb + i) * 16 + col;
#pragma unroll
        for (int r = 0; r < 4; ++r)
            g_Z[(size_t)(rowbase + r) * NTOT + ncol] = __float2bfloat16(acc[i][r]);
    }
}

// ---------------- conv3 Z-path: gather-aggregate (COUT=32) ----------------
template <int COUT, int NTOT>
__global__ __launch_bounds__(256) void agg_kernel(const int* __restrict__ src,
                                                  const void* __restrict__ bias,
                                                  void* __restrict__ out_ext, int N)
{
    int wid = threadIdx.x >> 6, lane = threadIdx.x & 63;
    int n = blockIdx.x * 4 + wid;
    if (n >= N) return;
    const bool bf = (g_isbf16 != 0);
    int e0 = g_offs[n], e1 = g_offs[n + 1];
    float acc = 0.0f;
    int o = lane & 31, bh = lane >> 5;
    for (int ei = e0; ei < e1; ++ei) {
        int e = g_eidx[ei];
        const __hip_bfloat16* zr = g_Z + (size_t)src[e] * NTOT;
#pragma unroll
        for (int bi = 0; bi < 4; ++bi) {
            int b = bh + bi * 2;
            float bs = g_basis[e * 8 + b];
            int wx = (int)g_widx[e * 8 + b];
            acc += bs * (float)zr[wx * 32 + o];
        }
    }
    acc += __shfl_xor(acc, 32, 64);
    if (lane >= 32) return;
    int deg = e1 - e0;
    float inv = 1.0f / (float)(deg < 1 ? 1 : deg);
    float v = acc * inv + (float)g_Z[(size_t)n * NTOT + 27 * COUT + o]
            + loadf(bias, o, bf);
    if (bf) ((__hip_bfloat16*)out_ext)[n * COUT + o] = __float2bfloat16(v);
    else    ((float*)out_ext)[n * COUT + o] = v;
}

// ---------------- BN stats ----------------
__global__ void bn_reduce(int n)
{
    int tid = threadIdx.x;
    int c = tid & 63;
    int r = tid >> 6;
    float s = 0.0f, s2 = 0.0f;
    for (int i = blockIdx.x * 4 + r; i < n; i += gridDim.x * 4) {
        float v = (float)g_h2[i * 64 + c];
        s += v; s2 += v * v;
    }
    __shared__ float b1s[256], b2s[256];
    b1s[tid] = s; b2s[tid] = s2;
    __syncthreads();
    if (r == 0) {
        s  = b1s[c] + b1s[c + 64] + b1s[c + 128] + b1s[c + 192];
        s2 = b2s[c] + b2s[c + 64] + b2s[c + 128] + b2s[c + 192];
        atomicAdd(&g_stats[c], s);
        atomicAdd(&g_stats[64 + c], s2);
    }
}

__global__ void bn_coef(const void* __restrict__ gamma,
                        const void* __restrict__ beta, int n)
{
    int c = threadIdx.x;
    const bool bf = (g_isbf16 != 0);
    float inv_n = 1.0f / (float)n;
    float mu = g_stats[c] * inv_n;
    float var = g_stats[64 + c] * inv_n - mu * mu;
    float A = rsqrtf(var + EPS) * loadf(gamma, c, bf);
    g_coef[c] = A;
    g_coef[64 + c] = loadf(beta, c, bf) - mu * A;
}

// ---------------- h3 = [elu(bn(h2)), pos, 0-pad] (96 ch) ----------------
__global__ void h3_build(const void* __restrict__ pos, int N)
{
    int t = blockIdx.x * blockDim.x + threadIdx.x;
    if (t >= N * 96) return;
    int n = t / 96, ch = t - n * 96;
    const bool bf = (g_isbf16 != 0);
    float v;
    if (ch < 64) {
        float h = (float)g_h2[n * 64 + ch];
        v = h * g_coef[ch] + g_coef[64 + ch];
        v = v > 0.0f ? v : expm1f(v);
    } else if (ch < 67) {
        v = loadf(pos, n * 3 + (ch - 64), bf);
    } else {
        v = 0.0f;
    }
    g_h3[(size_t)n * 96 + ch] = __float2bfloat16(v);
}

extern "C" void kernel_launch(void* const* d_in, const int* in_sizes, int n_in,
                              void* d_out, int out_size, void* d_ws, size_t ws_size,
                              hipStream_t stream)
{
    const void* x      = d_in[0];
    const int*  eindex = (const int*)d_in[1];
    const void* eattr  = d_in[2];
    const void* pos    = d_in[3];
    const void* W1     = d_in[4];
    const void* root1  = d_in[5];
    const void* b1     = d_in[6];
    const void* W2     = d_in[7];
    const void* root2  = d_in[8];
    const void* b2     = d_in[9];
    const void* gamma  = d_in[10];
    const void* beta   = d_in[11];
    const void* W3     = d_in[12];
    const void* root3  = d_in[13];
    const void* b3     = d_in[14];
    (void)d_ws; (void)ws_size; (void)n_in; (void)out_size;

    const int N = in_sizes[0] / 32;
    const int E = in_sizes[1] / 2;
    const int* srcp = eindex;
    const int* dstp = eindex + E;

    detect_kernel<<<1, 64, 0, stream>>>((const unsigned int*)x);
    init_kernel<<<(N + 255) / 256, 256, 0, stream>>>(N);

    int eb = (E + 255) / 256;
    basis_kernel<<<eb, 256, 0, stream>>>(eattr, dstp, E);
    int chunk = (N + 1023) / 1024;
    scan_kernel<<<1, 1024, 0, stream>>>(N, chunk);
    fill_kernel<<<eb, 256, 0, stream>>>(dstp, E);
    cast_x<<<(N * 32 + 255) / 256, 256, 0, stream>>>(x, N * 32);

    int nb16 = (N + 15) / 16;

    // ---- conv1: fused S-scheme, g_h0(32) -> g_h1(32), ELU ----
    {
        int wtot = (32 / 16) * 28 * 512;   // 28672
        prep_w_s<32><<<(wtot + 255) / 256, 256, 0, stream>>>(W1, root1, wtot);
        fused_conv<32, true, 0, 1><<<nb16, 1024, 0, stream>>>(srcp, b1, nullptr, N);
    }
    // ---- conv2: fused S-scheme, g_h1(32) -> g_h2(64), raw ----
    {
        int wtot = (64 / 16) * 28 * 512;   // 57344
        prep_w_s<64><<<(wtot + 255) / 256, 256, 0, stream>>>(W2, root2, wtot);
        fused_conv<64, false, 1, 2><<<nb16, 1024, 0, stream>>>(srcp, b2, nullptr, N);
    }
    // ---- BN + h3 build ----
    bn_reduce<<<120, 256, 0, stream>>>(N);
    bn_coef<<<1, 64, 0, stream>>>(gamma, beta, N);
    h3_build<<<(N * 96 + 255) / 256, 256, 0, stream>>>(pos, N);
    // ---- conv3: Z-scheme, h3(96) -> Z(896) -> out(32) ----
    {
        const int NTOT = 28 * 32, KPAD = 96, NPW = 4;
        int wtot = (NTOT / 16) * (KPAD / 32) * 512;   // 86016
        prep_w<67, 32, KPAD><<<(wtot + 255) / 256, 256, 0, stream>>>(W3, root3, wtot);
        int NTW = (NTOT / 16) / NPW;                  // 14
        int MT = nb16;
        int waves = MT * NTW;
        gemm_kernel<96, NTOT, KPAD, NPW><<<(waves + 3) / 4, 256, 0, stream>>>(MT, NTW);
        agg_kernel<32, NTOT><<<(N + 3) / 4, 256, 0, stream>>>(srcp, b3, d_out, N);
    }
}

// Round 9
// 569.114 us; speedup vs baseline: 1.7234x; 1.1459x over previous
//
#include <hip/hip_runtime.h>
#include <hip/hip_bf16.h>

// SplineCNN block.
// Edge metadata: one 32-B record per edge in CSR(dst) order:
//   d0=src, d1=wx[0..3] (u8), d2=wx[4..7], d3..d6 = basis[0..7] bf16 pairs.
// conv1, conv2 (CIN=32): fused S-scheme, 1024-thr / 16 nodes, wave-per-node:
//   32-edge record batches loaded into BOTH half-waves (so shfl source-lane
//   bh == receiver bh), x-gathers batched 8-deep; S[16][897] fp32 in LDS;
//   MFMA GEMM epilogue.  SPITCH=897 -> GEMM A-reads 2 lanes/bank (free).
// conv3: Z-scheme (Z = h3 @ [W3;root3] dense MFMA GEMM) + batched gather-agg.

#define EPS 1e-5f
#define MAXN 50176
#define MAXE 401408
#define SPITCH 897

typedef __attribute__((ext_vector_type(8))) short short8;
typedef __attribute__((ext_vector_type(4))) float floatx4;

__device__ int             g_deg[MAXN];
__device__ int             g_offs[MAXN + 1];
__device__ int             g_cursor[MAXN];
__device__ uint4           g_emeta[MAXE * 2];
__device__ __align__(16) __hip_bfloat16 g_h0[MAXN * 32];
__device__ __align__(16) __hip_bfloat16 g_h1[MAXN * 32];
__device__ __align__(16) __hip_bfloat16 g_h2[MAXN * 64];
__device__ __align__(16) __hip_bfloat16 g_h3[MAXN * 96];
__device__ __align__(16) __hip_bfloat16 g_Z[(size_t)MAXN * 896];
__device__ __align__(16) __hip_bfloat16 g_Wp[86016];
__device__ float           g_stats[128];
__device__ float           g_coef[128];
__device__ int             g_isbf16;

__device__ __forceinline__ float loadf(const void* p, int i, bool bf)
{
    return bf ? (float)((const __hip_bfloat16*)p)[i] : ((const float*)p)[i];
}
__device__ __forceinline__ float bf16f(unsigned int u)
{
    return __uint_as_float(u << 16);
}

// ---------------- wire dtype detection (one wave) ----------------
__global__ void detect_kernel(const unsigned int* __restrict__ w)
{
    int lane = threadIdx.x;
    int cnt = 0;
    for (int i = lane; i < 256; i += 64) {
        unsigned int lo = w[i] & 0xFFFFu;
        int ex = (int)((lo >> 7) & 0xFFu);
        if (lo == 0u || (ex >= 96 && ex <= 140)) cnt++;
    }
#pragma unroll
    for (int o = 1; o < 64; o <<= 1) cnt += __shfl_xor(cnt, o, 64);
    if (lane == 0) g_isbf16 = (cnt >= 200) ? 1 : 0;
}

// ---------------- zero-init scratch ----------------
__global__ void init_kernel(int n)
{
    int i = blockIdx.x * blockDim.x + threadIdx.x;
    if (i < n) { g_deg[i] = 0; g_cursor[i] = 0; }
    if (i < 128) g_stats[i] = 0.0f;
}

// ---------------- degree count ----------------
__global__ void count_kernel(const int* __restrict__ dst, int E)
{
    int e = blockIdx.x * blockDim.x + threadIdx.x;
    if (e >= E) return;
    atomicAdd(&g_deg[dst[e]], 1);
}

// ---------------- exclusive scan (single block) ----------------
__global__ void scan_kernel(int n, int chunk)
{
    __shared__ int buf[1024];
    int tid = threadIdx.x;
    int begin = tid * chunk;
    int end = begin + chunk; if (end > n) end = n;
    int s = 0;
    for (int i = begin; i < end; ++i) s += g_deg[i];
    buf[tid] = s;
    __syncthreads();
    for (int o = 1; o < 1024; o <<= 1) {
        int t = (tid >= o) ? buf[tid - o] : 0;
        __syncthreads();
        buf[tid] += t;
        __syncthreads();
    }
    int base = buf[tid] - s;
    for (int i = begin; i < end; ++i) { g_offs[i] = base; base += g_deg[i]; }
    if (tid == 1023) g_offs[n] = buf[1023];
}

// ---------------- basis + CSR fill: build 32-B edge records ----------------
__global__ void basis_fill(const void* __restrict__ attr,
                           const int* __restrict__ src,
                           const int* __restrict__ dst, int E)
{
    int e = blockIdx.x * blockDim.x + threadIdx.x;
    if (e >= E) return;
    const bool bf = (g_isbf16 != 0);
    float f[3];
    int lo[3];
#pragma unroll
    for (int d = 0; d < 3; ++d) {
        float a = loadf(attr, e * 3 + d, bf);
        float s = a * 3.0f;
        float l = floorf(s);
        lo[d] = (int)l;
        f[d] = s - l;
    }
    const int p3[3] = {1, 3, 9};
    unsigned int wxp0 = 0, wxp1 = 0;
    unsigned short bb[8];
#pragma unroll
    for (int b = 0; b < 8; ++b) {
        float w = 1.0f;
        int id = 0;
#pragma unroll
        for (int d = 0; d < 3; ++d) {
            int bit = (b >> d) & 1;
            w *= bit ? f[d] : (1.0f - f[d]);
            id += ((lo[d] + bit) % 3) * p3[d];
        }
        if (b < 4) wxp0 |= (unsigned int)id << (8 * b);
        else       wxp1 |= (unsigned int)id << (8 * (b - 4));
        union { __hip_bfloat16 h; unsigned short u; } cv;
        cv.h = __float2bfloat16(w);
        bb[b] = cv.u;
    }
    int d = dst[e];
    int p = atomicAdd(&g_cursor[d], 1);
    int slot = g_offs[d] + p;
    g_emeta[slot * 2] = make_uint4((unsigned int)src[e], wxp0, wxp1,
                                   (unsigned int)bb[0] | ((unsigned int)bb[1] << 16));
    g_emeta[slot * 2 + 1] = make_uint4(
        (unsigned int)bb[2] | ((unsigned int)bb[3] << 16),
        (unsigned int)bb[4] | ((unsigned int)bb[5] << 16),
        (unsigned int)bb[6] | ((unsigned int)bb[7] << 16), 0u);
}

// ---------------- cast external x -> g_h0 bf16 ----------------
__global__ void cast_x(const void* __restrict__ x, int total)
{
    int t = blockIdx.x * blockDim.x + threadIdx.x;
    if (t >= total) return;
    g_h0[t] = __float2bfloat16(loadf(x, t, g_isbf16 != 0));
}

// ---------------- pack [W;root] (K=896, CIN=32) into MFMA B-fragments ------
template <int COUT>
__global__ void prep_w_s(const void* __restrict__ W, const void* __restrict__ root,
                         int total)
{
    int t = blockIdx.x * blockDim.x + threadIdx.x;
    if (t >= total) return;
    const bool bf = (g_isbf16 != 0);
    int j = t & 7;
    int lane = (t >> 3) & 63;
    int rest = t >> 9;
    int kk = rest % 28;
    int nt = rest / 28;
    int k = kk * 32 + (lane >> 4) * 8 + j;
    int o = nt * 16 + (lane & 15);
    float v;
    if (k < 864) v = loadf(W, ((k >> 5) * 32 + (k & 31)) * COUT + o, bf);
    else         v = loadf(root, (k - 864) * COUT + o, bf);
    g_Wp[t] = __float2bfloat16(v);
}

// ---------------- fused conv (CIN=32): batched wave-per-node S + MFMA -------
// IN_SEL: 0 = g_h0, 1 = g_h1.  OUT_SEL: 1 = g_h1, 2 = g_h2, 0 = external.
template <int COUT, bool ELU, int IN_SEL, int OUT_SEL>
__global__ __launch_bounds__(1024, 8) void fused_conv(const void* __restrict__ bias,
                                                      void* __restrict__ out_ext,
                                                      int N)
{
    __shared__ float S[16 * SPITCH];
    int tid = threadIdx.x, wid = tid >> 6, lane = tid & 63;
    int nbase = blockIdx.x * 16;
    const bool bf = (g_isbf16 != 0);
    const unsigned short* xptr = (IN_SEL == 0) ? (const unsigned short*)g_h0
                                               : (const unsigned short*)g_h1;

    for (int i = tid; i < 16 * SPITCH; i += 1024) S[i] = 0.0f;
    __syncthreads();

    // ---- phase 1: wave `wid` aggregates node nbase+wid into S[wid] ----
    int n = nbase + wid;
    if (n < N) {
        float* Srow = S + wid * SPITCH;
        int c = lane & 31, bh = lane >> 5;
        float xs = bf16f(xptr[n * 32 + c]);
        if (bh == 0) Srow[864 + c] = xs;        // self-x -> root columns
        int e0 = g_offs[n], e1 = g_offs[n + 1];
        for (int base = e0; base < e1; base += 32) {
            int cnt = e1 - base; if (cnt > 32) cnt = 32;
            // both half-waves load the SAME 32 records: source-lane bh == receiver bh
            uint4 r0 = make_uint4(0, 0, 0, 0), r1 = make_uint4(0, 0, 0, 0);
            if ((lane & 31) < cnt) {
                size_t le = (size_t)(base + (lane & 31)) * 2;
                r0 = g_emeta[le];
                r1 = g_emeta[le + 1];
            }
            int selw4 = (int)(bh ? r0.z : r0.y);   // wx half for this bh
            int selba = (int)(bh ? r1.y : r0.w);   // basis pair 0 for this bh
            int selbb = (int)(bh ? r1.z : r1.x);   // basis pair 1 for this bh
            int srcv  = (int)r0.x;
            for (int j0 = 0; j0 < cnt; j0 += 8) {
                int jn = cnt - j0; if (jn > 8) jn = 8;
                unsigned short xv[8];
#pragma unroll
                for (int j = 0; j < 8; ++j) {
                    if (j < jn) {
                        int sn = __shfl(srcv, j0 + j, 64);
                        xv[j] = xptr[(size_t)sn * 32 + c];
                    }
                }
#pragma unroll
                for (int j = 0; j < 8; ++j) {
                    if (j >= jn) break;
                    int sl = j0 + j + (bh << 5);   // source lane in own half
                    unsigned int w4  = (unsigned int)__shfl(selw4, sl, 64);
                    unsigned int ba  = (unsigned int)__shfl(selba, sl, 64);
                    unsigned int bbv = (unsigned int)__shfl(selbb, sl, 64);
                    float xf = bf16f(xv[j]);
#pragma unroll
                    for (int bi = 0; bi < 4; ++bi) {
                        int wxv = (int)((w4 >> (8 * bi)) & 0xFFu);
                        unsigned int bbits = (((bi & 2) ? bbv : ba) >> (16 * (bi & 1))) & 0xFFFFu;
                        Srow[wxv * 32 + c] += bf16f(bbits) * xf;
                    }
                }
            }
        }
        int deg = e1 - e0;
        float inv = 1.0f / (float)(deg < 1 ? 1 : deg);
        for (int cc = lane; cc < 864; cc += 64) Srow[cc] *= inv;
    }
    __syncthreads();

    // ---- phase 2: wave w = col-tile w of GEMM 16 x 896 @ 896 x COUT ----
    if (wid * 16 < COUT) {
        int m = lane & 15, quad = lane >> 4;
        const float* Abase = S + m * SPITCH + quad * 8;
        floatx4 acc = {};
#pragma unroll
        for (int kk = 0; kk < 28; ++kk) {
            union { __hip_bfloat16 h[8]; short8 v; } u;
            const float* ap = Abase + kk * 32;
#pragma unroll
            for (int j = 0; j < 8; ++j) u.h[j] = __float2bfloat16(ap[j]);
            const short* bp = (const short*)g_Wp +
                ((size_t)(wid * 28 + kk) * 64 + lane) * 8;
            short8 b = *(const short8*)bp;
            acc = __builtin_amdgcn_mfma_f32_16x16x32_bf16(u.v, b, acc, 0, 0, 0);
        }
        int o = wid * 16 + (lane & 15);
        float bval = loadf(bias, o, bf);
#pragma unroll
        for (int r = 0; r < 4; ++r) {
            int slot = quad * 4 + r;
            int nn = nbase + slot;
            if (nn >= N) continue;
            float v = acc[r] + bval;
            if (ELU) v = v > 0.0f ? v : expm1f(v);
            if (OUT_SEL == 1)      g_h1[nn * 32 + o] = __float2bfloat16(v);
            else if (OUT_SEL == 2) g_h2[nn * 64 + o] = __float2bfloat16(v);
            else {
                if (bf) ((__hip_bfloat16*)out_ext)[nn * COUT + o] = __float2bfloat16(v);
                else    ((float*)out_ext)[nn * COUT + o] = v;
            }
        }
    }
}

// ---------------- conv3 Z-path: pack W3+root3 into B-fragments ----------------
template <int CIN, int COUT, int KPAD>
__global__ void prep_w(const void* __restrict__ W, const void* __restrict__ root,
                       int total)
{
    int t = blockIdx.x * blockDim.x + threadIdx.x;
    if (t >= total) return;
    const bool bf = (g_isbf16 != 0);
    const int KB = KPAD / 32;
    int j = t & 7;
    int lane = (t >> 3) & 63;
    int rest = t >> 9;
    int kk = rest % KB;
    int nt = rest / KB;
    int k = kk * 32 + (lane >> 4) * 8 + j;
    int ncol = nt * 16 + (lane & 15);
    int kw = ncol / COUT;
    int o = ncol - kw * COUT;
    float v = 0.0f;
    if (k < CIN)
        v = (kw < 27) ? loadf(W, (kw * CIN + k) * COUT + o, bf)
                      : loadf(root, k * COUT + o, bf);
    g_Wp[t] = __float2bfloat16(v);
}

// ---------------- conv3 Z-path: dense GEMM Z = h3 @ Wp ----------------
template <int STRIDE, int NTOT, int KPAD, int NPW>
__global__ __launch_bounds__(256) void gemm_kernel(int MT, int NTW)
{
    int gid = blockIdx.x * 256 + threadIdx.x;
    int gw = gid >> 6, lane = gid & 63;
    if (gw >= MT * NTW) return;
    int mt = gw % MT;
    int ntb = (gw / MT) * NPW;
    int m = lane & 15, quad = lane >> 4;
    const short* hrow = (const short*)g_h3 + (size_t)(mt * 16 + m) * STRIDE;
    floatx4 acc[NPW] = {};
    const int KB = KPAD / 32;
#pragma unroll
    for (int kk = 0; kk < KB; ++kk) {
        short8 a = *(const short8*)(hrow + kk * 32 + quad * 8);
#pragma unroll
        for (int i = 0; i < NPW; ++i) {
            const short* bp = (const short*)g_Wp +
                (((size_t)(ntb + i) * KB + kk) * 64 + lane) * 8;
            short8 b = *(const short8*)bp;
            acc[i] = __builtin_amdgcn_mfma_f32_16x16x32_bf16(a, b, acc[i], 0, 0, 0);
        }
    }
    int col = lane & 15;
    int rowbase = mt * 16 + quad * 4;
#pragma unroll
    for (int i = 0; i < NPW; ++i) {
        int ncol = (ntb + i) * 16 + col;
#pragma unroll
        for (int r = 0; r < 4; ++r)
            g_Z[(size_t)(rowbase + r) * NTOT + ncol] = __float2bfloat16(acc[i][r]);
    }
}

// ---------------- conv3: batched gather-aggregate (COUT=32) ----------------
template <int COUT, int NTOT>
__global__ __launch_bounds__(256) void agg_kernel(const void* __restrict__ bias,
                                                  void* __restrict__ out_ext, int N)
{
    int wid = threadIdx.x >> 6, lane = threadIdx.x & 63;
    int n = blockIdx.x * 4 + wid;
    if (n >= N) return;
    const bool bf = (g_isbf16 != 0);
    const unsigned short* zp = (const unsigned short*)g_Z;
    int e0 = g_offs[n], e1 = g_offs[n + 1];
    float acc = 0.0f;
    int o = lane & 31, bh = lane >> 5;
    for (int base = e0; base < e1; base += 32) {
        int cnt = e1 - base; if (cnt > 32) cnt = 32;
        uint4 r0 = make_uint4(0, 0, 0, 0), r1 = make_uint4(0, 0, 0, 0);
        if ((lane & 31) < cnt) {
            size_t le = (size_t)(base + (lane & 31)) * 2;
            r0 = g_emeta[le];
            r1 = g_emeta[le + 1];
        }
        int selw4 = (int)(bh ? r0.z : r0.y);
        int selba = (int)(bh ? r1.y : r0.w);
        int selbb = (int)(bh ? r1.z : r1.x);
        int srcv  = (int)r0.x;
#pragma unroll 2
        for (int j = 0; j < cnt; ++j) {
            int sl = j + (bh << 5);
            int sn = __shfl(srcv, j, 64);
            unsigned int w4  = (unsigned int)__shfl(selw4, sl, 64);
            unsigned int ba  = (unsigned int)__shfl(selba, sl, 64);
            unsigned int bbv = (unsigned int)__shfl(selbb, sl, 64);
            const unsigned short* zr = zp + (size_t)sn * NTOT;
#pragma unroll
            for (int bi = 0; bi < 4; ++bi) {
                int wxv = (int)((w4 >> (8 * bi)) & 0xFFu);
                unsigned int bbits = (((bi & 2) ? bbv : ba) >> (16 * (bi & 1))) & 0xFFFFu;
                acc += bf16f(bbits) * bf16f(zr[wxv * 32 + o]);
            }
        }
    }
    acc += __shfl_xor(acc, 32, 64);
    if (lane >= 32) return;
    int deg = e1 - e0;
    float inv = 1.0f / (float)(deg < 1 ? 1 : deg);
    float v = acc * inv + bf16f(zp[(size_t)n * NTOT + 27 * COUT + o])
            + loadf(bias, o, bf);
    if (bf) ((__hip_bfloat16*)out_ext)[n * COUT + o] = __float2bfloat16(v);
    else    ((float*)out_ext)[n * COUT + o] = v;
}

// ---------------- BN stats ----------------
__global__ void bn_reduce(int n)
{
    int tid = threadIdx.x;
    int c = tid & 63;
    int r = tid >> 6;
    float s = 0.0f, s2 = 0.0f;
    for (int i = blockIdx.x * 4 + r; i < n; i += gridDim.x * 4) {
        float v = (float)g_h2[i * 64 + c];
        s += v; s2 += v * v;
    }
    __shared__ float b1s[256], b2s[256];
    b1s[tid] = s; b2s[tid] = s2;
    __syncthreads();
    if (r == 0) {
        s  = b1s[c] + b1s[c + 64] + b1s[c + 128] + b1s[c + 192];
        s2 = b2s[c] + b2s[c + 64] + b2s[c + 128] + b2s[c + 192];
        atomicAdd(&g_stats[c], s);
        atomicAdd(&g_stats[64 + c], s2);
    }
}

__global__ void bn_coef(const void* __restrict__ gamma,
                        const void* __restrict__ beta, int n)
{
    int c = threadIdx.x;
    const bool bf = (g_isbf16 != 0);
    float inv_n = 1.0f / (float)n;
    float mu = g_stats[c] * inv_n;
    float var = g_stats[64 + c] * inv_n - mu * mu;
    float A = rsqrtf(var + EPS) * loadf(gamma, c, bf);
    g_coef[c] = A;
    g_coef[64 + c] = loadf(beta, c, bf) - mu * A;
}

// ---------------- h3 = [elu(bn(h2)), pos, 0-pad] (96 ch) ----------------
__global__ void h3_build(const void* __restrict__ pos, int N)
{
    int t = blockIdx.x * blockDim.x + threadIdx.x;
    if (t >= N * 96) return;
    int n = t / 96, ch = t - n * 96;
    const bool bf = (g_isbf16 != 0);
    float v;
    if (ch < 64) {
        float h = (float)g_h2[n * 64 + ch];
        v = h * g_coef[ch] + g_coef[64 + ch];
        v = v > 0.0f ? v : expm1f(v);
    } else if (ch < 67) {
        v = loadf(pos, n * 3 + (ch - 64), bf);
    } else {
        v = 0.0f;
    }
    g_h3[(size_t)n * 96 + ch] = __float2bfloat16(v);
}

extern "C" void kernel_launch(void* const* d_in, const int* in_sizes, int n_in,
                              void* d_out, int out_size, void* d_ws, size_t ws_size,
                              hipStream_t stream)
{
    const void* x      = d_in[0];
    const int*  eindex = (const int*)d_in[1];
    const void* eattr  = d_in[2];
    const void* pos    = d_in[3];
    const void* W1     = d_in[4];
    const void* root1  = d_in[5];
    const void* b1     = d_in[6];
    const void* W2     = d_in[7];
    const void* root2  = d_in[8];
    const void* b2     = d_in[9];
    const void* gamma  = d_in[10];
    const void* beta   = d_in[11];
    const void* W3     = d_in[12];
    const void* root3  = d_in[13];
    const void* b3     = d_in[14];
    (void)d_ws; (void)ws_size; (void)n_in; (void)out_size;

    const int N = in_sizes[0] / 32;
    const int E = in_sizes[1] / 2;
    const int* srcp = eindex;
    const int* dstp = eindex + E;

    detect_kernel<<<1, 64, 0, stream>>>((const unsigned int*)x);
    init_kernel<<<(N + 255) / 256, 256, 0, stream>>>(N);

    int eb = (E + 255) / 256;
    count_kernel<<<eb, 256, 0, stream>>>(dstp, E);
    int chunk = (N + 1023) / 1024;
    scan_kernel<<<1, 1024, 0, stream>>>(N, chunk);
    basis_fill<<<eb, 256, 0, stream>>>(eattr, srcp, dstp, E);
    cast_x<<<(N * 32 + 255) / 256, 256, 0, stream>>>(x, N * 32);

    int nb16 = (N + 15) / 16;

    // ---- conv1: fused S-scheme, g_h0(32) -> g_h1(32), ELU ----
    {
        int wtot = (32 / 16) * 28 * 512;   // 28672
        prep_w_s<32><<<(wtot + 255) / 256, 256, 0, stream>>>(W1, root1, wtot);
        fused_conv<32, true, 0, 1><<<nb16, 1024, 0, stream>>>(b1, nullptr, N);
    }
    // ---- conv2: fused S-scheme, g_h1(32) -> g_h2(64), raw ----
    {
        int wtot = (64 / 16) * 28 * 512;   // 57344
        prep_w_s<64><<<(wtot + 255) / 256, 256, 0, stream>>>(W2, root2, wtot);
        fused_conv<64, false, 1, 2><<<nb16, 1024, 0, stream>>>(b2, nullptr, N);
    }
    // ---- BN + h3 build ----
    bn_reduce<<<120, 256, 0, stream>>>(N);
    bn_coef<<<1, 64, 0, stream>>>(gamma, beta, N);
    h3_build<<<(N * 96 + 255) / 256, 256, 0, stream>>>(pos, N);
    // ---- conv3: Z-scheme, h3(96) -> Z(896) -> out(32) ----
    {
        const int NTOT = 28 * 32, KPAD = 96, NPW = 4;
        int wtot = (NTOT / 16) * (KPAD / 32) * 512;   // 86016
        prep_w<67, 32, KPAD><<<(wtot + 255) / 256, 256, 0, stream>>>(W3, root3, wtot);
        int NTW = (NTOT / 16) / NPW;                  // 14
        int MT = nb16;
        int waves = MT * NTW;
        gemm_kernel<96, NTOT, KPAD, NPW><<<(waves + 3) / 4, 256, 0, stream>>>(MT, NTW);
        agg_kernel<32, NTOT><<<(N + 3) / 4, 256, 0, stream>>>(b3, d_out, N);
    }
}